// Round 1
// baseline (187.973 us; speedup 1.0000x reference)
//
#include <hip/hip_runtime.h>
#include <hip/hip_bf16.h>
#include <math.h>

typedef unsigned int uint;
typedef unsigned short ushort;
typedef __attribute__((ext_vector_type(8))) short short8;
typedef __attribute__((ext_vector_type(4))) float f32x4;

#define K_DIM 8192
#define ROWB 16384  // K_DIM * 2 bytes per row of XT / YT

// ws layout (bytes):
//   0      : double sums[4]            (xy, xx, yy)
//   256    : float  csx[2048]          (column sums of x)
//   8448   : float  csy[1024]          (column sums of y)
//   16384  : ushort XT[2048][8192]     centered x^T, bf16, swizzled  (32 MB)
//   33570816: ushort YT[1024][8192]    centered y^T, bf16, swizzled  (16 MB)
// total ≈ 50.3 MB

__device__ __forceinline__ ushort f2bf(float f) {
  uint x = __float_as_uint(f);
  uint r = (x + 0x7fffu + ((x >> 16) & 1u)) >> 16;  // RTNE
  return (ushort)r;
}

__device__ __forceinline__ void async16(const void* g, void* l) {
  __builtin_amdgcn_global_load_lds(
      (const __attribute__((address_space(1))) unsigned int*)g,
      (__attribute__((address_space(3))) unsigned int*)l, 16, 0, 0);
}

__global__ __launch_bounds__(256) void zero_k(double* sums, float* csx, float* csy) {
  int t = threadIdx.x;
  if (t < 4) sums[t] = 0.0;
  for (int i = t; i < 2048; i += 256) csx[i] = 0.f;
  for (int i = t; i < 1024; i += 256) csy[i] = 0.f;
}

// 192 blocks: 0..127 -> x (8 colblk x 16 rowblk), 128..191 -> y (4 colblk x 16 rowblk)
__global__ __launch_bounds__(256) void colsum_k(const float* __restrict__ x,
                                                const float* __restrict__ y,
                                                float* csx, float* csy) {
  int bid = blockIdx.x, t = threadIdx.x;
  const float* src; float* dst; int C, cb, rb;
  if (bid < 128) { src = x; dst = csx; C = 2048; cb = bid & 7; rb = bid >> 3; }
  else { int b = bid - 128; src = y; dst = csy; C = 1024; cb = b & 3; rb = b >> 2; }
  int col = cb * 256 + t;
  size_t base = (size_t)(rb * 512) * (size_t)C + (size_t)col;
  float s = 0.f;
  for (int r = 0; r < 512; r++) s += src[base + (size_t)r * C];
  atomicAdd(&dst[col], s);
}

// Center + transpose + bf16 + swizzle. 64x64 tiles.
// blocks 0..4095 -> x (mt = bid>>7 in 0..31, kt = bid&127), 4096..6143 -> y (mt 0..15)
__global__ __launch_bounds__(256) void centerT_k(const float* __restrict__ x,
                                                 const float* __restrict__ y,
                                                 const float* __restrict__ csx,
                                                 const float* __restrict__ csy,
                                                 ushort* XT, ushort* YT) {
  __shared__ float tile[64][65];
  int bid = blockIdx.x, t = threadIdx.x;
  const float* src; const float* cs; char* dst; int C, mt, kt;
  if (bid < 4096) { src = x; cs = csx; dst = (char*)XT; C = 2048; mt = bid >> 7; kt = bid & 127; }
  else { int b = bid - 4096; src = y; cs = csy; dst = (char*)YT; C = 1024; mt = b >> 7; kt = b & 127; }
  int m0 = mt * 64, k0 = kt * 64;

#pragma unroll
  for (int rep = 0; rep < 16; rep++) {
    int idx = rep * 256 + t;
    int kr = idx >> 6, mc = idx & 63;
    tile[kr][mc] = src[(size_t)(k0 + kr) * C + (size_t)(m0 + mc)];
  }
  __syncthreads();

  const float inv_n = 1.0f / 8192.0f;
#pragma unroll
  for (int rep = 0; rep < 2; rep++) {
    int uid = rep * 256 + t;
    int ml = uid >> 3, u = uid & 7;   // ml: m within tile, u: 8-elem k-unit
    int m = m0 + ml;
    float mean = cs[m] * inv_n;
    uint wds[4];
#pragma unroll
    for (int j = 0; j < 4; j++) {
      float f0 = tile[u * 8 + 2 * j][ml] - mean;
      float f1 = tile[u * 8 + 2 * j + 1][ml] - mean;
      wds[j] = (uint)f2bf(f0) | ((uint)f2bf(f1) << 16);
    }
    // swizzle: data unit u stored at position u ^ (m&7) within the 128B chunk
    size_t off = (size_t)m * ROWB + (size_t)(k0 >> 6) * 128 + (size_t)((u ^ (m & 7)) << 4);
    uint4 v; v.x = wds[0]; v.y = wds[1]; v.z = wds[2]; v.w = wds[3];
    *(uint4*)(dst + off) = v;
  }
}

// Fused triple-GEMM Frobenius kernel. 300 blocks:
//   0..127   : XY  (16 x 8 tiles of 128x128), slot 0, weight 1
//   128..263 : XX upper-tri (16 tri = 136),   slot 1, weight 2 off-diag
//   264..299 : YY upper-tri (8 tri = 36),     slot 2, weight 2 off-diag
__global__ __launch_bounds__(256, 2) void gemm_fro_k(const ushort* __restrict__ XT,
                                                     const ushort* __restrict__ YT,
                                                     double* sums) {
  __shared__ char lds[32768];
  __shared__ double part[4];
  char* ldsA = lds;
  char* ldsB = lds + 16384;

  int bid = blockIdx.x;
  const char* Ab; const char* Bb; int m0, n0, slot; double wgt;
  if (bid < 128) {
    int mt = bid >> 3, nt = bid & 7;
    Ab = (const char*)XT; Bb = (const char*)YT;
    m0 = mt * 128; n0 = nt * 128; wgt = 1.0; slot = 0;
  } else if (bid < 264) {
    int idx = bid - 128; int ti = 0;
    while (idx >= 16 - ti) { idx -= 16 - ti; ti++; }
    int tj = ti + idx;
    Ab = (const char*)XT; Bb = (const char*)XT;
    m0 = ti * 128; n0 = tj * 128; wgt = (ti == tj) ? 1.0 : 2.0; slot = 1;
  } else {
    int idx = bid - 264; int ti = 0;
    while (idx >= 8 - ti) { idx -= 8 - ti; ti++; }
    int tj = ti + idx;
    Ab = (const char*)YT; Bb = (const char*)YT;
    m0 = ti * 128; n0 = tj * 128; wgt = (ti == tj) ? 1.0 : 2.0; slot = 2;
  }

  int t = threadIdx.x;
  int row8 = t >> 3;      // 0..31 : staging row within 32-row group
  int u = t & 7;          // staging 16B unit
  int w = t >> 6;         // wave 0..3 -> 2x2 of 64x64
  int lane = t & 63;
  int wm = (w >> 1) * 64, wn = (w & 1) * 64;
  int lr = lane & 15, lk = lane >> 4;

  f32x4 acc[4][4];
#pragma unroll
  for (int i = 0; i < 4; i++)
#pragma unroll
    for (int j = 0; j < 4; j++)
      acc[i][j] = (f32x4){0.f, 0.f, 0.f, 0.f};

  const size_t abase = (size_t)m0 * ROWB + (size_t)(u * 16);
  const size_t bbase = (size_t)n0 * ROWB + (size_t)(u * 16);

  for (int s = 0; s < K_DIM / 64; s++) {
    __syncthreads();  // previous compute done before LDS overwrite
    size_t koff = (size_t)s * 128;
#pragma unroll
    for (int c = 0; c < 4; c++) {
      int row = c * 32 + row8;
      async16(Ab + abase + (size_t)row * ROWB + koff, ldsA + row * 128 + u * 16);
      async16(Bb + bbase + (size_t)row * ROWB + koff, ldsB + row * 128 + u * 16);
    }
    __syncthreads();  // compiler drains vmcnt(0) before barrier

#pragma unroll
    for (int ks = 0; ks < 2; ks++) {
      short8 a[4], b[4];
#pragma unroll
      for (int mi = 0; mi < 4; mi++) {
        int row = wm + mi * 16 + lr;
        int ku = ks * 4 + lk;
        a[mi] = *(const short8*)(ldsA + row * 128 + ((ku ^ (row & 7)) << 4));
      }
#pragma unroll
      for (int nj = 0; nj < 4; nj++) {
        int row = wn + nj * 16 + lr;
        int ku = ks * 4 + lk;
        b[nj] = *(const short8*)(ldsB + row * 128 + ((ku ^ (row & 7)) << 4));
      }
#pragma unroll
      for (int mi = 0; mi < 4; mi++)
#pragma unroll
        for (int nj = 0; nj < 4; nj++)
          acc[mi][nj] = __builtin_amdgcn_mfma_f32_16x16x32_bf16(a[mi], b[nj], acc[mi][nj], 0, 0, 0);
    }
  }

  // Frobenius partial: sum of squares of all accumulator elements
  double local = 0.0;
#pragma unroll
  for (int mi = 0; mi < 4; mi++)
#pragma unroll
    for (int nj = 0; nj < 4; nj++)
#pragma unroll
      for (int e = 0; e < 4; e++) {
        double v = (double)acc[mi][nj][e];
        local += v * v;
      }

  for (int off = 32; off; off >>= 1) local += __shfl_down(local, off, 64);
  if (lane == 0) part[w] = local;
  __syncthreads();
  if (t == 0) {
    double tot = (part[0] + part[1]) + (part[2] + part[3]);
    atomicAdd(&sums[slot], wgt * tot);
  }
}

__global__ void finalize_k(const double* sums, float* out) {
  double xy = sums[0], xx = sums[1], yy = sums[2];
  out[0] = (float)(xy / (sqrt(xx * yy) + 1e-8));
}

extern "C" void kernel_launch(void* const* d_in, const int* in_sizes, int n_in,
                              void* d_out, int out_size, void* d_ws, size_t ws_size,
                              hipStream_t stream) {
  (void)in_sizes; (void)n_in; (void)out_size; (void)ws_size;
  const float* x = (const float*)d_in[0];
  const float* y = (const float*)d_in[1];
  float* out = (float*)d_out;
  char* ws = (char*)d_ws;
  double* sums = (double*)ws;
  float* csx = (float*)(ws + 256);
  float* csy = (float*)(ws + 8448);
  ushort* XT = (ushort*)(ws + 16384);
  ushort* YT = (ushort*)(ws + 33570816);

  zero_k<<<1, 256, 0, stream>>>(sums, csx, csy);
  colsum_k<<<192, 256, 0, stream>>>(x, y, csx, csy);
  centerT_k<<<6144, 256, 0, stream>>>(x, y, csx, csy, XT, YT);
  gemm_fro_k<<<300, 256, 0, stream>>>(XT, YT, sums);
  finalize_k<<<1, 1, 0, stream>>>(sums, out);
}

// Round 2
// 184.813 us; speedup vs baseline: 1.0171x; 1.0171x over previous
//
#include <hip/hip_runtime.h>
#include <hip/hip_bf16.h>
#include <math.h>

typedef unsigned int uint;
typedef unsigned short ushort;
typedef __attribute__((ext_vector_type(8))) short short8;
typedef __attribute__((ext_vector_type(4))) float f32x4;

#define K_DIM 8192
#define ROWB 16384  // K_DIM * 2 bytes per row of XT / YT

// ws layout (bytes):
//   0      : double sums[4]            (xy, xx, yy)
//   256    : float  csx[2048]          (column sums of x)
//   8448   : float  csy[1024]          (column sums of y)
//   16384  : ushort XT[2048][8192]     centered x^T, bf16, swizzled  (32 MB)
//   33570816: ushort YT[1024][8192]    centered y^T, bf16, swizzled  (16 MB)
// total ≈ 50.3 MB (proven to fit in R1)

__device__ __forceinline__ ushort f2bf(float f) {
  uint x = __float_as_uint(f);
  uint r = (x + 0x7fffu + ((x >> 16) & 1u)) >> 16;  // RTNE
  return (ushort)r;
}

__device__ __forceinline__ void async16(const void* g, void* l) {
  __builtin_amdgcn_global_load_lds(
      (const __attribute__((address_space(1))) unsigned int*)g,
      (__attribute__((address_space(3))) unsigned int*)l, 16, 0, 0);
}

__global__ __launch_bounds__(256) void zero_k(double* sums, float* csx, float* csy) {
  int t = threadIdx.x;
  if (t < 4) sums[t] = 0.0;
  for (int i = t; i < 2048; i += 256) csx[i] = 0.f;
  for (int i = t; i < 1024; i += 256) csy[i] = 0.f;
}

// 192 blocks: 0..127 -> x (8 colblk x 16 rowblk), 128..191 -> y (4 colblk x 16 rowblk)
__global__ __launch_bounds__(256) void colsum_k(const float* __restrict__ x,
                                                const float* __restrict__ y,
                                                float* csx, float* csy) {
  int bid = blockIdx.x, t = threadIdx.x;
  const float* src; float* dst; int C, cb, rb;
  if (bid < 128) { src = x; dst = csx; C = 2048; cb = bid & 7; rb = bid >> 3; }
  else { int b = bid - 128; src = y; dst = csy; C = 1024; cb = b & 3; rb = b >> 2; }
  int col = cb * 256 + t;
  size_t base = (size_t)(rb * 512) * (size_t)C + (size_t)col;
  float s = 0.f;
  for (int r = 0; r < 512; r++) s += src[base + (size_t)r * C];
  atomicAdd(&dst[col], s);
}

// Center + transpose + bf16 + swizzle. 64x64 tiles.
// blocks 0..4095 -> x (mt = bid>>7 in 0..31, kt = bid&127), 4096..6143 -> y (mt 0..15)
__global__ __launch_bounds__(256) void centerT_k(const float* __restrict__ x,
                                                 const float* __restrict__ y,
                                                 const float* __restrict__ csx,
                                                 const float* __restrict__ csy,
                                                 ushort* XT, ushort* YT) {
  __shared__ float tile[64][65];
  int bid = blockIdx.x, t = threadIdx.x;
  const float* src; const float* cs; char* dst; int C, mt, kt;
  if (bid < 4096) { src = x; cs = csx; dst = (char*)XT; C = 2048; mt = bid >> 7; kt = bid & 127; }
  else { int b = bid - 4096; src = y; cs = csy; dst = (char*)YT; C = 1024; mt = b >> 7; kt = b & 127; }
  int m0 = mt * 64, k0 = kt * 64;

#pragma unroll
  for (int rep = 0; rep < 16; rep++) {
    int idx = rep * 256 + t;
    int kr = idx >> 6, mc = idx & 63;
    tile[kr][mc] = src[(size_t)(k0 + kr) * C + (size_t)(m0 + mc)];
  }
  __syncthreads();

  const float inv_n = 1.0f / 8192.0f;
#pragma unroll
  for (int rep = 0; rep < 2; rep++) {
    int uid = rep * 256 + t;
    int ml = uid >> 3, u = uid & 7;   // ml: m within tile, u: 8-elem k-unit
    int m = m0 + ml;
    float mean = cs[m] * inv_n;
    uint wds[4];
#pragma unroll
    for (int j = 0; j < 4; j++) {
      float f0 = tile[u * 8 + 2 * j][ml] - mean;
      float f1 = tile[u * 8 + 2 * j + 1][ml] - mean;
      wds[j] = (uint)f2bf(f0) | ((uint)f2bf(f1) << 16);
    }
    // swizzle: data unit u stored at position u ^ (m&7) within the 128B chunk
    size_t off = (size_t)m * ROWB + (size_t)(k0 >> 6) * 128 + (size_t)((u ^ (m & 7)) << 4);
    uint4 v; v.x = wds[0]; v.y = wds[1]; v.z = wds[2]; v.w = wds[3];
    *(uint4*)(dst + off) = v;
  }
}

// Fused triple-GEMM Frobenius kernel. 300 blocks x 512 threads (8 waves):
//   0..127   : XY  (16 x 8 tiles of 128x128), slot 0, weight 1
//   128..263 : XX upper-tri (16 tri = 136),   slot 1, weight 2 off-diag
//   264..299 : YY upper-tri (8 tri = 36),     slot 2, weight 2 off-diag
// Wave grid: 2(M) x 4(N); each wave owns 64 rows x 32 cols = 4x2 frags of 16x16.
__global__ __launch_bounds__(512, 2) void gemm_fro_k(const ushort* __restrict__ XT,
                                                     const ushort* __restrict__ YT,
                                                     double* sums) {
  __shared__ char lds[32768];
  __shared__ double part[8];
  char* ldsA = lds;
  char* ldsB = lds + 16384;

  int bid = blockIdx.x;
  const char* Ab; const char* Bb; int m0, n0, slot; double wgt;
  if (bid < 128) {
    int mt = bid >> 3, nt = bid & 7;
    Ab = (const char*)XT; Bb = (const char*)YT;
    m0 = mt * 128; n0 = nt * 128; wgt = 1.0; slot = 0;
  } else if (bid < 264) {
    int idx = bid - 128; int ti = 0;
    while (idx >= 16 - ti) { idx -= 16 - ti; ti++; }
    int tj = ti + idx;
    Ab = (const char*)XT; Bb = (const char*)XT;
    m0 = ti * 128; n0 = tj * 128; wgt = (ti == tj) ? 1.0 : 2.0; slot = 1;
  } else {
    int idx = bid - 264; int ti = 0;
    while (idx >= 8 - ti) { idx -= 8 - ti; ti++; }
    int tj = ti + idx;
    Ab = (const char*)YT; Bb = (const char*)YT;
    m0 = ti * 128; n0 = tj * 128; wgt = (ti == tj) ? 1.0 : 2.0; slot = 2;
  }

  int t = threadIdx.x;
  int row8 = t >> 3;      // 0..63 : staging row within 64-row group
  int u = t & 7;          // staging 16B unit
  int w = t >> 6;         // wave 0..7
  int lane = t & 63;
  int wm = (w >> 2) * 64, wn = (w & 3) * 32;   // 2x4 wave grid
  int lr = lane & 15, lk = lane >> 4;

  f32x4 acc[4][2];
#pragma unroll
  for (int i = 0; i < 4; i++)
#pragma unroll
    for (int j = 0; j < 2; j++)
      acc[i][j] = (f32x4){0.f, 0.f, 0.f, 0.f};

  const size_t abase = (size_t)m0 * ROWB + (size_t)(u * 16);
  const size_t bbase = (size_t)n0 * ROWB + (size_t)(u * 16);

  for (int s = 0; s < K_DIM / 64; s++) {
    __syncthreads();  // previous compute done before LDS overwrite
    size_t koff = (size_t)s * 128;
#pragma unroll
    for (int c = 0; c < 2; c++) {
      int row = c * 64 + row8;
      async16(Ab + abase + (size_t)row * ROWB + koff, ldsA + row * 128 + u * 16);
      async16(Bb + bbase + (size_t)row * ROWB + koff, ldsB + row * 128 + u * 16);
    }
    __syncthreads();  // compiler drains vmcnt(0) before barrier

#pragma unroll
    for (int ks = 0; ks < 2; ks++) {
      short8 a[4], b[2];
#pragma unroll
      for (int mi = 0; mi < 4; mi++) {
        int row = wm + mi * 16 + lr;
        int ku = ks * 4 + lk;
        a[mi] = *(const short8*)(ldsA + row * 128 + ((ku ^ (row & 7)) << 4));
      }
#pragma unroll
      for (int nj = 0; nj < 2; nj++) {
        int row = wn + nj * 16 + lr;
        int ku = ks * 4 + lk;
        b[nj] = *(const short8*)(ldsB + row * 128 + ((ku ^ (row & 7)) << 4));
      }
#pragma unroll
      for (int mi = 0; mi < 4; mi++)
#pragma unroll
        for (int nj = 0; nj < 2; nj++)
          acc[mi][nj] = __builtin_amdgcn_mfma_f32_16x16x32_bf16(a[mi], b[nj], acc[mi][nj], 0, 0, 0);
    }
  }

  // Frobenius partial: sum of squares of all accumulator elements
  double local = 0.0;
#pragma unroll
  for (int mi = 0; mi < 4; mi++)
#pragma unroll
    for (int nj = 0; nj < 2; nj++)
#pragma unroll
      for (int e = 0; e < 4; e++) {
        double v = (double)acc[mi][nj][e];
        local += v * v;
      }

  for (int off = 32; off; off >>= 1) local += __shfl_down(local, off, 64);
  if (lane == 0) part[w] = local;
  __syncthreads();
  if (t == 0) {
    double tot = 0.0;
#pragma unroll
    for (int i = 0; i < 8; i++) tot += part[i];
    atomicAdd(&sums[slot], wgt * tot);
  }
}

__global__ void finalize_k(const double* sums, float* out) {
  double xy = sums[0], xx = sums[1], yy = sums[2];
  out[0] = (float)(xy / (sqrt(xx * yy) + 1e-8));
}

extern "C" void kernel_launch(void* const* d_in, const int* in_sizes, int n_in,
                              void* d_out, int out_size, void* d_ws, size_t ws_size,
                              hipStream_t stream) {
  (void)in_sizes; (void)n_in; (void)out_size; (void)ws_size;
  const float* x = (const float*)d_in[0];
  const float* y = (const float*)d_in[1];
  float* out = (float*)d_out;
  char* ws = (char*)d_ws;
  double* sums = (double*)ws;
  float* csx = (float*)(ws + 256);
  float* csy = (float*)(ws + 8448);
  ushort* XT = (ushort*)(ws + 16384);
  ushort* YT = (ushort*)(ws + 33570816);

  zero_k<<<1, 256, 0, stream>>>(sums, csx, csy);
  colsum_k<<<192, 256, 0, stream>>>(x, y, csx, csy);
  centerT_k<<<6144, 256, 0, stream>>>(x, y, csx, csy, XT, YT);
  gemm_fro_k<<<300, 512, 0, stream>>>(XT, YT, sums);
  finalize_k<<<1, 1, 0, stream>>>(sums, out);
}